// Round 13
// baseline (260.642 us; speedup 1.0000x reference)
//
#include <hip/hip_runtime.h>
#include <hip/hip_bf16.h>
#include <math.h>

#define D_MODEL 1024
#define N_HEADS 16
#define HEAD_DIM 64
#define SEQ 2048
#define BATCH 2

typedef __attribute__((ext_vector_type(8))) short short8;
typedef __attribute__((ext_vector_type(4))) float f32x4;
typedef _Float16 half8 __attribute__((ext_vector_type(8)));
typedef __fp16 fp16x2 __attribute__((ext_vector_type(2)));

// scale folded into Q at projection: (1/sqrt(1024)) * log2(e)
#define QSCALE 0.0450842200277948f

__device__ __forceinline__ unsigned short f2bf(float x) {
  union { float f; unsigned u; } v; v.f = x;
  unsigned r = v.u + 0x7FFFu + ((v.u >> 16) & 1u);
  return (unsigned short)(r >> 16);
}
__device__ __forceinline__ float bf2f(unsigned short h) {
  return __uint_as_float((unsigned)h << 16);
}
// packed fp32x2 -> fp16x2, single v_cvt_pkrtz_f16_f32
__device__ __forceinline__ unsigned pkh(float a, float b) {
  union { fp16x2 h; unsigned u; } v;
  v.h = __builtin_amdgcn_cvt_pkrtz(a, b);
  return v.u;
}
// Truncation hi + RNE lo: pair represents x to ~2^-17 relative.
__device__ __forceinline__ void split2(float x, unsigned short& h, unsigned short& l) {
  union { float f; unsigned u; } v; v.f = x;
  h = (unsigned short)(v.u >> 16);
  l = f2bf(x - __uint_as_float(v.u & 0xFFFF0000u));
}
__device__ __forceinline__ void glds16(const unsigned short* g, unsigned short* l) {
  __builtin_amdgcn_global_load_lds(
      (const __attribute__((address_space(1))) void*)g,
      (__attribute__((address_space(3))) void*)l, 16, 0, 0);
}

// ---------------------------------------------------------------------------
// Fused prep: x -> Xhi/Xlo (z<4), weight transpose+split (z=4..7).
// ---------------------------------------------------------------------------
__global__ __launch_bounds__(256) void prep_kernel(
    const float* __restrict__ x, const float* __restrict__ qw,
    const float* __restrict__ kw, const float* __restrict__ vw,
    const float* __restrict__ ow, unsigned short* __restrict__ Xhi,
    unsigned short* __restrict__ Xlo, unsigned short* __restrict__ Wqk_hi,
    unsigned short* __restrict__ Wqk_lo, unsigned short* __restrict__ vwT,
    unsigned short* __restrict__ owT) {
  const int z = blockIdx.z;
  const size_t wmat = (size_t)D_MODEL * D_MODEL;
  if (z < 4) {
    const size_t off = (size_t)z * wmat +
        ((size_t)blockIdx.y * 32 + blockIdx.x) * 1024 + (size_t)threadIdx.x * 4;
    const float4 v = *(const float4*)&x[off];
    unsigned short h0, h1, h2, h3, l0, l1, l2, l3;
    split2(v.x, h0, l0); split2(v.y, h1, l1);
    split2(v.z, h2, l2); split2(v.w, h3, l3);
    uint2 ph, pl;
    ph.x = (unsigned)h0 | ((unsigned)h1 << 16);
    ph.y = (unsigned)h2 | ((unsigned)h3 << 16);
    pl.x = (unsigned)l0 | ((unsigned)l1 << 16);
    pl.y = (unsigned)l2 | ((unsigned)l3 << 16);
    *(uint2*)&Xhi[off] = ph;
    *(uint2*)&Xlo[off] = pl;
    return;
  }
  __shared__ float t[32][33];
  const float* W = (z == 4) ? qw : (z == 5) ? kw : (z == 6) ? vw : ow;
  unsigned short* Thi = (z == 4) ? Wqk_hi : (z == 5) ? Wqk_hi + wmat
                        : (z == 6) ? vwT : owT;
  unsigned short* Tlo = (z == 4) ? Wqk_lo : Wqk_lo + wmat;  // used when z<6
  const bool LO = (z < 6);
  const int k0 = blockIdx.x * 32, n0 = blockIdx.y * 32;
  const int tx = threadIdx.x & 31, ty = threadIdx.x >> 5;
#pragma unroll
  for (int i = 0; i < 32; i += 8)
    t[ty + i][tx] = W[(size_t)(k0 + ty + i) * D_MODEL + n0 + tx];
  __syncthreads();
#pragma unroll
  for (int i = 0; i < 32; i += 8) {
    unsigned short h, l;
    split2(t[tx][ty + i], h, l);
    const size_t off = (size_t)(n0 + ty + i) * D_MODEL + k0 + tx;
    Thi[off] = h;
    if (LO) Tlo[off] = l;
  }
}

// ---------------------------------------------------------------------------
// 128(m)x64(n) MFMA GEMM, hi/lo precision (Q+K projection). Grid (32,32) =
// 1024 blocks = 4 blocks/CU (16 waves/CU, 2x the 128x128 version's TLP).
// BK=32 single-stage 2-barrier m97 pattern; LDS 24 KB. Wave w owns the
// 64x32 quadrant (row (w>>1)*64, col (w&1)*32); acc 4x2.
// B stacked [2*D_MODEL][D_MODEL]: rows 0..1023 = qw^T, 1024.. = kw^T.
// ---------------------------------------------------------------------------
__global__ __launch_bounds__(256) void gemm_qk64_kernel(
    const unsigned short* __restrict__ Xhi, const unsigned short* __restrict__ Xlo,
    const unsigned short* __restrict__ Whi, const unsigned short* __restrict__ Wlo,
    unsigned short* __restrict__ Qhi, unsigned short* __restrict__ Qlo,
    unsigned short* __restrict__ Khi, unsigned short* __restrict__ Klo) {
  __shared__ __align__(16) unsigned short Ah[128 * 32], Al[128 * 32];
  __shared__ __align__(16) unsigned short Bh[64 * 32], Bl[64 * 32];
  const int tid = threadIdx.x;
  const int lane = tid & 63, w = tid >> 6;
  const int lq = lane & 15, g = lane >> 4;
  const int n0 = blockIdx.x * 64;    // within stacked 2048
  const int m0 = blockIdx.y * 128;
  const int wm = (w >> 1) * 64, wn = (w & 1) * 32;

  f32x4 acc[4][2];
#pragma unroll
  for (int mi = 0; mi < 4; ++mi)
#pragma unroll
    for (int ni = 0; ni < 2; ++ni) acc[mi][ni] = (f32x4){0.f, 0.f, 0.f, 0.f};

  for (int k0 = 0; k0 < D_MODEL; k0 += 32) {
    __syncthreads();
#pragma unroll
    for (int it = 0; it < 2; ++it) {
      const int e = it * 256 + tid;      // 0..511 -> 128 rows x 4 col-chunks
      const int r = e >> 2, c8 = (e & 3) * 8;
      glds16(&Xhi[(size_t)(m0 + r) * D_MODEL + k0 + c8], &Ah[e * 8]);
      glds16(&Xlo[(size_t)(m0 + r) * D_MODEL + k0 + c8], &Al[e * 8]);
    }
    {
      const int r = tid >> 2, c8 = (tid & 3) * 8;  // 64 rows x 4 col-chunks
      glds16(&Whi[(size_t)(n0 + r) * D_MODEL + k0 + c8], &Bh[tid * 8]);
      glds16(&Wlo[(size_t)(n0 + r) * D_MODEL + k0 + c8], &Bl[tid * 8]);
    }
    __syncthreads();

    short8 ah[4], al[4], bh[2], bl[2];
#pragma unroll
    for (int i = 0; i < 4; ++i) {
      ah[i] = *(const short8*)&Ah[(wm + i * 16 + lq) * 32 + g * 8];
      al[i] = *(const short8*)&Al[(wm + i * 16 + lq) * 32 + g * 8];
    }
#pragma unroll
    for (int j = 0; j < 2; ++j) {
      bh[j] = *(const short8*)&Bh[(wn + j * 16 + lq) * 32 + g * 8];
      bl[j] = *(const short8*)&Bl[(wn + j * 16 + lq) * 32 + g * 8];
    }
#pragma unroll
    for (int mi = 0; mi < 4; ++mi)
#pragma unroll
      for (int ni = 0; ni < 2; ++ni) {
        acc[mi][ni] = __builtin_amdgcn_mfma_f32_16x16x32_bf16(ah[mi], bh[ni], acc[mi][ni], 0, 0, 0);
        acc[mi][ni] = __builtin_amdgcn_mfma_f32_16x16x32_bf16(ah[mi], bl[ni], acc[mi][ni], 0, 0, 0);
        acc[mi][ni] = __builtin_amdgcn_mfma_f32_16x16x32_bf16(al[mi], bh[ni], acc[mi][ni], 0, 0, 0);
      }
  }

  const bool isQ = (n0 < D_MODEL);
  unsigned short* Dhi = isQ ? Qhi : Khi;
  unsigned short* Dlo = isQ ? Qlo : Klo;
  const float sc = isQ ? QSCALE : 1.0f;
  const int nbase = n0 & (D_MODEL - 1);
#pragma unroll
  for (int mi = 0; mi < 4; ++mi)
#pragma unroll
    for (int ni = 0; ni < 2; ++ni) {
      const int gm = m0 + wm + mi * 16 + g * 4;
      const int gn = nbase + wn + ni * 16 + lq;
#pragma unroll
      for (int r = 0; r < 4; ++r) {
        unsigned short h, l;
        split2(acc[mi][ni][r] * sc, h, l);
        Dhi[(size_t)(gm + r) * D_MODEL + gn] = h;
        Dlo[(size_t)(gm + r) * D_MODEL + gn] = l;
      }
    }
}

// ---------------------------------------------------------------------------
// 128x64 plain bf16 GEMM (512 blocks = 2/CU), 2 k-tiles per barrier.
// CM 0: fp32 C row-major. CM 2: fp16 C transposed into Vt[b][h][dh][s].
// ---------------------------------------------------------------------------
template <int CM>
__global__ __launch_bounds__(256) void gemm_bn64_kernel(
    const unsigned short* __restrict__ A, const unsigned short* __restrict__ B,
    void* __restrict__ C) {
  __shared__ __align__(16) unsigned short Ah[2][128 * 32], Bh[2][64 * 32];
  const int tid = threadIdx.x;
  const int lane = tid & 63, w = tid >> 6;
  const int lq = lane & 15, g = lane >> 4;
  const int n0 = blockIdx.x * 64;
  const int m0 = blockIdx.y * 128;
  const int wm = (w >> 1) * 64, wn = (w & 1) * 32;

  f32x4 acc[4][2];
#pragma unroll
  for (int mi = 0; mi < 4; ++mi)
#pragma unroll
    for (int ni = 0; ni < 2; ++ni) acc[mi][ni] = (f32x4){0.f, 0.f, 0.f, 0.f};

  for (int k0 = 0; k0 < D_MODEL; k0 += 64) {
    __syncthreads();
#pragma unroll
    for (int half = 0; half < 2; ++half) {
      const int kc = k0 + half * 32;
#pragma unroll
      for (int it = 0; it < 2; ++it) {
        const int e = it * 256 + tid;
        const int r = e >> 2, c8 = (e & 3) * 8;
        glds16(&A[(size_t)(m0 + r) * D_MODEL + kc + c8], &Ah[half][e * 8]);
      }
      glds16(&B[(size_t)(n0 + (tid >> 2)) * D_MODEL + kc + (tid & 3) * 8],
             &Bh[half][tid * 8]);
    }
    __syncthreads();

#pragma unroll
    for (int half = 0; half < 2; ++half) {
      short8 ah[4], bh[2];
#pragma unroll
      for (int i = 0; i < 4; ++i)
        ah[i] = *(const short8*)&Ah[half][(wm + i * 16 + lq) * 32 + g * 8];
#pragma unroll
      for (int j = 0; j < 2; ++j)
        bh[j] = *(const short8*)&Bh[half][(wn + j * 16 + lq) * 32 + g * 8];
#pragma unroll
      for (int mi = 0; mi < 4; ++mi)
#pragma unroll
        for (int ni = 0; ni < 2; ++ni)
          acc[mi][ni] = __builtin_amdgcn_mfma_f32_16x16x32_bf16(ah[mi], bh[ni], acc[mi][ni], 0, 0, 0);
    }
  }

#pragma unroll
  for (int mi = 0; mi < 4; ++mi)
#pragma unroll
    for (int ni = 0; ni < 2; ++ni) {
      const int gm = m0 + wm + mi * 16 + g * 4;
      const int gn = n0 + wn + ni * 16 + lq;
      if constexpr (CM == 0) {
        float* Cf = (float*)C;
#pragma unroll
        for (int r = 0; r < 4; ++r)
          Cf[(size_t)(gm + r) * D_MODEL + gn] = acc[mi][ni][r];
      } else {  // Vt[b][h][dh][s] fp16; rows gm..gm+3 are 4 consecutive s
        const int bb = gm >> 11, s = gm & 2047;
        const int hh = gn >> 6, dh = gn & 63;
        uint2 pk;
        pk.x = pkh(acc[mi][ni][0], acc[mi][ni][1]);
        pk.y = pkh(acc[mi][ni][2], acc[mi][ni][3]);
        unsigned short* Vt = (unsigned short*)C;
        *(uint2*)&Vt[(((size_t)bb * N_HEADS + hh) * HEAD_DIM + dh) * SEQ + s] = pk;
      }
    }
}

// ---------------------------------------------------------------------------
// Split-K MFMA flash attention (causal), chunk C=12 kt-tiles. UNCHANGED
// from round 11 (proven: 83-89 us, VGPR 76, no spill).
// ---------------------------------------------------------------------------
#define PSTR 72  // LDS row stride in elements (64 data + 8 pad)

__global__ __launch_bounds__(256) void attn_mfma_kernel(
    const unsigned short* __restrict__ Qhi, const unsigned short* __restrict__ Qlo,
    const unsigned short* __restrict__ Khi, const unsigned short* __restrict__ Klo,
    const unsigned short* __restrict__ Vt,   // fp16 [B][H][HEAD_DIM][S]
    unsigned short* __restrict__ O,          // bf16 [B*S][D_MODEL] head-merged
    unsigned short* __restrict__ Opart,      // bf16 [1536][4096]
    float* __restrict__ Mpart, float* __restrict__ Lpart) {  // [1536][64]
  __shared__ __align__(16) unsigned short Khs[64 * PSTR];
  __shared__ __align__(16) unsigned short Kls[64 * PSTR];
  __shared__ __align__(16) unsigned short Vs[64 * PSTR];   // fp16
  __shared__ __align__(16) unsigned short Ps[64 * PSTR];   // fp16

  const int tid = threadIdx.x;
  const int lane = tid & 63;
  const int w = tid >> 6;
  const int lq = lane & 15;
  const int g = lane >> 4;
  const int q_blk = w * 16 + lq;
  const int x = blockIdx.x;
  const int h = blockIdx.y;
  const int b = blockIdx.z;

  int qt, kb, ke;
  if (x < 12)      { qt = 12 + x;                 kb = 0;  ke = 12; }
  else if (x < 28) { const int i = x - 12; qt = 24 + (i >> 1);
                     kb = (i & 1) * 12;           ke = kb + 12; }
  else if (x < 40) { qt = 23 - (x - 28);          kb = 12; ke = qt + 1; }
  else if (x < 48) { qt = 31 - (x - 40);          kb = 24; ke = qt + 1; }
  else             { qt = 59 - x;                 kb = 0;  ke = qt + 1; }
  const bool direct = (x >= 48);
  const int qr0 = qt * 64;

  const size_t base = ((size_t)b * SEQ) * D_MODEL + (size_t)h * HEAD_DIM;
  const unsigned short* Vtb = Vt + ((size_t)(b * N_HEADS + h) * HEAD_DIM) * SEQ;

  const size_t qoff = base + (size_t)(qr0 + q_blk) * D_MODEL;
  const short8 qh0 = *(const short8*)&Qhi[qoff + g * 8];
  const short8 qh1 = *(const short8*)&Qhi[qoff + g * 8 + 32];
  const short8 ql0 = *(const short8*)&Qlo[qoff + g * 8];
  const short8 ql1 = *(const short8*)&Qlo[qoff + g * 8 + 32];

  f32x4 Ot[4];
#pragma unroll
  for (int mt = 0; mt < 4; ++mt) Ot[mt] = (f32x4){0.f, 0.f, 0.f, 0.f};
  float m_run = -INFINITY, l_run = 0.f;

  for (int kt = kb; kt < ke; ++kt) {
    const int kr0 = kt * 64;
    __syncthreads();  // previous iteration's LDS reads done
#pragma unroll
    for (int it = 0; it < 2; ++it) {
      const int id = it * 256 + tid;
      const int r = id >> 3, c8 = (id & 7) * 8;
      const size_t koff = base + (size_t)(kr0 + r) * D_MODEL + c8;
      *(uint4*)&Khs[r * PSTR + c8] = *(const uint4*)&Khi[koff];
      *(uint4*)&Kls[r * PSTR + c8] = *(const uint4*)&Klo[koff];
      *(uint4*)&Vs[r * PSTR + c8]  = *(const uint4*)&Vtb[(size_t)r * SEQ + kr0 + c8];
    }
    __syncthreads();

    // S^T[k][q]: 4 k-subtiles x 6 MFMAs (hi/lo 3-term over two d-halves)
    f32x4 S[4];
#pragma unroll
    for (int st = 0; st < 4; ++st) {
      const unsigned short* khr = &Khs[(st * 16 + lq) * PSTR];
      const unsigned short* klr = &Kls[(st * 16 + lq) * PSTR];
      const short8 kh0 = *(const short8*)&khr[g * 8];
      const short8 kh1 = *(const short8*)&khr[g * 8 + 32];
      const short8 kl0 = *(const short8*)&klr[g * 8];
      const short8 kl1 = *(const short8*)&klr[g * 8 + 32];
      f32x4 s = (f32x4){0.f, 0.f, 0.f, 0.f};
      s = __builtin_amdgcn_mfma_f32_16x16x32_bf16(kh0, qh0, s, 0, 0, 0);
      s = __builtin_amdgcn_mfma_f32_16x16x32_bf16(kh1, qh1, s, 0, 0, 0);
      s = __builtin_amdgcn_mfma_f32_16x16x32_bf16(kh0, ql0, s, 0, 0, 0);
      s = __builtin_amdgcn_mfma_f32_16x16x32_bf16(kh1, ql1, s, 0, 0, 0);
      s = __builtin_amdgcn_mfma_f32_16x16x32_bf16(kl0, qh0, s, 0, 0, 0);
      s = __builtin_amdgcn_mfma_f32_16x16x32_bf16(kl1, qh1, s, 0, 0, 0);
      S[st] = s;
    }
    // V-fragments fp16 (independent of softmax; issue early)
    half8 vf0[4], vf1[4];
#pragma unroll
    for (int mt = 0; mt < 4; ++mt) {
      vf0[mt] = *(const half8*)&Vs[(mt * 16 + lq) * PSTR + g * 8];
      vf1[mt] = *(const half8*)&Vs[(mt * 16 + lq) * PSTR + g * 8 + 32];
    }

    // online softmax (exp2 domain; scale folded into Q)
    const bool diag = (kt == qt);
    float sv[16];
    float tmax = -3.0e38f;
#pragma unroll
    for (int st = 0; st < 4; ++st)
#pragma unroll
      for (int r = 0; r < 4; ++r) {
        float s = S[st][r];
        if (diag && (st * 16 + g * 4 + r) > q_blk) s = -1.0e30f;
        sv[st * 4 + r] = s;
        tmax = fmaxf(tmax, s);
      }
    tmax = fmaxf(tmax, __shfl_xor(tmax, 16));
    tmax = fmaxf(tmax, __shfl_xor(tmax, 32));
    const float m_new = fmaxf(m_run, tmax);
    const float alpha = exp2f(m_run - m_new);  // first iter: exp2(-inf)=0
    m_run = m_new;
    float psum = 0.f;
#pragma unroll
    for (int i = 0; i < 16; ++i) {
      sv[i] = exp2f(sv[i] - m_new);
      psum += sv[i];
    }
    // write P early (wave-private row, fp16 packed); bookkeeping hides latency
#pragma unroll
    for (int st = 0; st < 4; ++st) {
      uint2 pk;
      pk.x = pkh(sv[st * 4 + 0], sv[st * 4 + 1]);
      pk.y = pkh(sv[st * 4 + 2], sv[st * 4 + 3]);
      *(uint2*)&Ps[q_blk * PSTR + st * 16 + g * 4] = pk;
    }
    psum += __shfl_xor(psum, 16);
    psum += __shfl_xor(psum, 32);
    l_run = l_run * alpha + psum;
#pragma unroll
    for (int mt = 0; mt < 4; ++mt) {
      Ot[mt][0] *= alpha; Ot[mt][1] *= alpha;
      Ot[mt][2] *= alpha; Ot[mt][3] *= alpha;
    }
    const half8 pf0 = *(const half8*)&Ps[q_blk * PSTR + g * 8];
    const half8 pf1 = *(const half8*)&Ps[q_blk * PSTR + g * 8 + 32];
#pragma unroll
    for (int mt = 0; mt < 4; ++mt) {
      Ot[mt] = __builtin_amdgcn_mfma_f32_16x16x32_f16(vf0[mt], pf0, Ot[mt], 0, 0, 0);
      Ot[mt] = __builtin_amdgcn_mfma_f32_16x16x32_f16(vf1[mt], pf1, Ot[mt], 0, 0, 0);
    }
  }

  if (direct) {  // whole tile computed here: normalized direct write
    const float inv_l = 1.0f / l_run;
    unsigned short* orow = &O[qoff];
#pragma unroll
    for (int mt = 0; mt < 4; ++mt) {
      uint2 pk;
      pk.x = (unsigned)f2bf(Ot[mt][0] * inv_l) | ((unsigned)f2bf(Ot[mt][1] * inv_l) << 16);
      pk.y = (unsigned)f2bf(Ot[mt][2] * inv_l) | ((unsigned)f2bf(Ot[mt][3] * inv_l) << 16);
      *(uint2*)&orow[mt * 16 + g * 4] = pk;
    }
  } else {  // split chunk: unnormalized partial + (m,l)
    const int c = kb / 12;
    const int pbase = (qt < 24) ? ((qt - 12) * 2 + c) : (24 + (qt - 24) * 3 + c);
    const int pidx = (b * N_HEADS + h) * 48 + pbase;
    unsigned short* op = &Opart[(size_t)pidx * 4096 + (size_t)q_blk * 64];
#pragma unroll
    for (int mt = 0; mt < 4; ++mt) {
      uint2 pk;
      pk.x = (unsigned)f2bf(Ot[mt][0]) | ((unsigned)f2bf(Ot[mt][1]) << 16);
      pk.y = (unsigned)f2bf(Ot[mt][2]) | ((unsigned)f2bf(Ot[mt][3]) << 16);
      *(uint2*)&op[mt * 16 + g * 4] = pk;
    }
    if (g == 0) {  // one lane per q row (m/l wave-uniform across g)
      Mpart[pidx * 64 + q_blk] = m_run;
      Lpart[pidx * 64 + q_blk] = l_run;
    }
  }
}

// ---------------------------------------------------------------------------
// Merge nc (2 or 3) split-K partials per q-tile (qt>=12), exp2-domain.
// ---------------------------------------------------------------------------
__global__ __launch_bounds__(256) void attn_merge_kernel(
    const unsigned short* __restrict__ Opart, const float* __restrict__ Mpart,
    const float* __restrict__ Lpart, unsigned short* __restrict__ O) {
  const int qt = 12 + blockIdx.x;
  const int h = blockIdx.y, b = blockIdx.z;
  const int nc = (qt < 24) ? 2 : 3;
  const int pbase = (qt < 24) ? ((qt - 12) * 2) : (24 + (qt - 24) * 3);
  const int pidx0 = (b * N_HEADS + h) * 48 + pbase;
  const int t = threadIdx.x;
  const int row = t >> 2;
  const int c0 = (t & 3) * 16;

  float mi[3], li[3];
  float m = -INFINITY;
  for (int c = 0; c < nc; ++c) {
    mi[c] = Mpart[(pidx0 + c) * 64 + row];
    li[c] = Lpart[(pidx0 + c) * 64 + row];
    m = fmaxf(m, mi[c]);
  }
  float a[3], denom = 0.f;
  for (int c = 0; c < nc; ++c) {
    a[c] = exp2f(mi[c] - m);
    denom += a[c] * li[c];
  }
  const float inv = 1.0f / denom;

  float accv[16];
#pragma unroll
  for (int j = 0; j < 16; ++j) accv[j] = 0.f;
  for (int c = 0; c < nc; ++c) {
    const unsigned short* src =
        &Opart[(size_t)(pidx0 + c) * 4096 + (size_t)row * 64 + c0];
    const uint4 v0 = *(const uint4*)&src[0];
    const uint4 v1 = *(const uint4*)&src[8];
    const unsigned* u = (const unsigned*)&v0;
#pragma unroll
    for (int j = 0; j < 4; ++j) {
      accv[j * 2 + 0] += a[c] * bf2f((unsigned short)(u[j] & 0xFFFF));
      accv[j * 2 + 1] += a[c] * bf2f((unsigned short)(u[j] >> 16));
    }
    const unsigned* u1 = (const unsigned*)&v1;
#pragma unroll
    for (int j = 0; j < 4; ++j) {
      accv[8 + j * 2 + 0] += a[c] * bf2f((unsigned short)(u1[j] & 0xFFFF));
      accv[8 + j * 2 + 1] += a[c] * bf2f((unsigned short)(u1[j] >> 16));
    }
  }
  unsigned short* dst = &O[((size_t)b * SEQ + (size_t)qt * 64 + row) * D_MODEL +
                           (size_t)h * HEAD_DIM + c0];
  uint4 o0, o1;
  unsigned* po = (unsigned*)&o0;
#pragma unroll
  for (int j = 0; j < 4; ++j)
    po[j] = (unsigned)f2bf(accv[j * 2] * inv) |
            ((unsigned)f2bf(accv[j * 2 + 1] * inv) << 16);
  unsigned* p1 = (unsigned*)&o1;
#pragma unroll
  for (int j = 0; j < 4; ++j)
    p1[j] = (unsigned)f2bf(accv[8 + j * 2] * inv) |
            ((unsigned)f2bf(accv[8 + j * 2 + 1] * inv) << 16);
  *(uint4*)&dst[0] = o0;
  *(uint4*)&dst[8] = o1;
}

// ---------------------------------------------------------------------------
extern "C" void kernel_launch(void* const* d_in, const int* in_sizes, int n_in,
                              void* d_out, int out_size, void* d_ws, size_t ws_size,
                              hipStream_t stream) {
  const float* x  = (const float*)d_in[0];
  const float* qw = (const float*)d_in[1];
  const float* kw = (const float*)d_in[2];
  const float* vw = (const float*)d_in[3];
  const float* ow = (const float*)d_in[4];
  float* out = (float*)d_out;

  const int M = BATCH * SEQ;                       // 4096
  const size_t mat  = (size_t)M * D_MODEL;         // 4M elems
  const size_t wmat = (size_t)D_MODEL * D_MODEL;   // 1M elems

  // ws (ushort units), ~62.8 MB total (unchanged from r11):
  unsigned short* ws     = (unsigned short*)d_ws;
  unsigned short* Xhi    = ws;                     // [0,4M)  ; later At
  unsigned short* Xlo    = Xhi + mat;              // [4M,8M) ; later Vt (fp16)
  unsigned short* Wqk_hi = Xlo + mat;              // [8M,10M); later Opart
  unsigned short* Wqk_lo = Wqk_hi + 2 * wmat;      // [10M,12M); later Opart
  unsigned short* vwT    = Wqk_lo + 2 * wmat;      // [12M,13M); later Opart
  unsigned short* pad0   = vwT + wmat;             // [13M,14M); Opart tail
  unsigned short* Qhi    = pad0 + wmat;            // [14M,18M)
  unsigned short* Qlo    = Qhi + mat;              // [18M,22M)
  unsigned short* Khi    = Qlo + mat;              // [22M,26M)
  unsigned short* Klo    = Khi + mat;              // [26M,30M)
  unsigned short* owT    = Klo + mat;              // [30M,31M)
  float*          Mpart  = (float*)(owT + wmat);   // 1536*64 fp32 (384 KB)
  float*          Lpart  = Mpart + 1536 * 64;      // 384 KB
  unsigned short* At     = Xhi;     // alias (Xhi dead after V-GEMM)
  unsigned short* Vt     = Xlo;     // alias (Xlo dead after QK-GEMM)
  unsigned short* Opart  = Wqk_hi;  // alias [8M,14M) = 1536 x 4096 shorts

  prep_kernel<<<dim3(32, 32, 8), 256, 0, stream>>>(
      x, qw, kw, vw, ow, Xhi, Xlo, Wqk_hi, Wqk_lo, vwT, owT);

  gemm_qk64_kernel<<<dim3(32, 32), 256, 0, stream>>>(
      Xhi, Xlo, Wqk_hi, Wqk_lo, Qhi, Qlo, Khi, Klo);

  gemm_bn64_kernel<2><<<dim3(16, 32), 256, 0, stream>>>(Xhi, vwT, Vt);

  attn_mfma_kernel<<<dim3(60, N_HEADS, BATCH), 256, 0, stream>>>(
      Qhi, Qlo, Khi, Klo, Vt, At, Opart, Mpart, Lpart);

  attn_merge_kernel<<<dim3(20, N_HEADS, BATCH), 256, 0, stream>>>(
      Opart, Mpart, Lpart, At);

  gemm_bn64_kernel<0><<<dim3(16, 32), 256, 0, stream>>>(At, owT, out);
}

// Round 14
// 246.470 us; speedup vs baseline: 1.0575x; 1.0575x over previous
//
#include <hip/hip_runtime.h>
#include <hip/hip_bf16.h>
#include <math.h>

#define D_MODEL 1024
#define N_HEADS 16
#define HEAD_DIM 64
#define SEQ 2048
#define BATCH 2

typedef __attribute__((ext_vector_type(8))) short short8;
typedef __attribute__((ext_vector_type(4))) float f32x4;
typedef _Float16 half8 __attribute__((ext_vector_type(8)));
typedef __fp16 fp16x2 __attribute__((ext_vector_type(2)));

// scale folded into Q at projection: (1/sqrt(1024)) * log2(e)
#define QSCALE 0.0450842200277948f

__device__ __forceinline__ unsigned short f2bf(float x) {
  union { float f; unsigned u; } v; v.f = x;
  unsigned r = v.u + 0x7FFFu + ((v.u >> 16) & 1u);
  return (unsigned short)(r >> 16);
}
__device__ __forceinline__ float bf2f(unsigned short h) {
  return __uint_as_float((unsigned)h << 16);
}
// packed fp32x2 -> fp16x2, single v_cvt_pkrtz_f16_f32
__device__ __forceinline__ unsigned pkh(float a, float b) {
  union { fp16x2 h; unsigned u; } v;
  v.h = __builtin_amdgcn_cvt_pkrtz(a, b);
  return v.u;
}
// Truncation hi + RNE lo: pair represents x to ~2^-17 relative.
__device__ __forceinline__ void split2(float x, unsigned short& h, unsigned short& l) {
  union { float f; unsigned u; } v; v.f = x;
  h = (unsigned short)(v.u >> 16);
  l = f2bf(x - __uint_as_float(v.u & 0xFFFF0000u));
}
__device__ __forceinline__ void glds16(const unsigned short* g, unsigned short* l) {
  __builtin_amdgcn_global_load_lds(
      (const __attribute__((address_space(1))) void*)g,
      (__attribute__((address_space(3))) void*)l, 16, 0, 0);
}

// ---------------------------------------------------------------------------
// Fused prep: x -> Xhi/Xlo (z<4), weight transpose+split (z=4..7).
// ---------------------------------------------------------------------------
__global__ __launch_bounds__(256) void prep_kernel(
    const float* __restrict__ x, const float* __restrict__ qw,
    const float* __restrict__ kw, const float* __restrict__ vw,
    const float* __restrict__ ow, unsigned short* __restrict__ Xhi,
    unsigned short* __restrict__ Xlo, unsigned short* __restrict__ Wqk_hi,
    unsigned short* __restrict__ Wqk_lo, unsigned short* __restrict__ vwT,
    unsigned short* __restrict__ owT) {
  const int z = blockIdx.z;
  const size_t wmat = (size_t)D_MODEL * D_MODEL;
  if (z < 4) {
    const size_t off = (size_t)z * wmat +
        ((size_t)blockIdx.y * 32 + blockIdx.x) * 1024 + (size_t)threadIdx.x * 4;
    const float4 v = *(const float4*)&x[off];
    unsigned short h0, h1, h2, h3, l0, l1, l2, l3;
    split2(v.x, h0, l0); split2(v.y, h1, l1);
    split2(v.z, h2, l2); split2(v.w, h3, l3);
    uint2 ph, pl;
    ph.x = (unsigned)h0 | ((unsigned)h1 << 16);
    ph.y = (unsigned)h2 | ((unsigned)h3 << 16);
    pl.x = (unsigned)l0 | ((unsigned)l1 << 16);
    pl.y = (unsigned)l2 | ((unsigned)l3 << 16);
    *(uint2*)&Xhi[off] = ph;
    *(uint2*)&Xlo[off] = pl;
    return;
  }
  __shared__ float t[32][33];
  const float* W = (z == 4) ? qw : (z == 5) ? kw : (z == 6) ? vw : ow;
  unsigned short* Thi = (z == 4) ? Wqk_hi : (z == 5) ? Wqk_hi + wmat
                        : (z == 6) ? vwT : owT;
  unsigned short* Tlo = (z == 4) ? Wqk_lo : Wqk_lo + wmat;  // used when z<6
  const bool LO = (z < 6);
  const int k0 = blockIdx.x * 32, n0 = blockIdx.y * 32;
  const int tx = threadIdx.x & 31, ty = threadIdx.x >> 5;
#pragma unroll
  for (int i = 0; i < 32; i += 8)
    t[ty + i][tx] = W[(size_t)(k0 + ty + i) * D_MODEL + n0 + tx];
  __syncthreads();
#pragma unroll
  for (int i = 0; i < 32; i += 8) {
    unsigned short h, l;
    split2(t[tx][ty + i], h, l);
    const size_t off = (size_t)(n0 + ty + i) * D_MODEL + k0 + tx;
    Thi[off] = h;
    if (LO) Tlo[off] = l;
  }
}

// ---------------------------------------------------------------------------
// 128x128 MFMA GEMM, hi/lo precision (Q+K projection), 2 k-tiles staged per
// barrier (16 barriers; grid 512 caps occupancy at 2 blocks/CU so the
// 64 KB LDS is free). Best-measured qk structure (r12).
// ---------------------------------------------------------------------------
__global__ __launch_bounds__(256) void gemm128_qk_kernel(
    const unsigned short* __restrict__ Xhi, const unsigned short* __restrict__ Xlo,
    const unsigned short* __restrict__ Whi, const unsigned short* __restrict__ Wlo,
    unsigned short* __restrict__ Qhi, unsigned short* __restrict__ Qlo,
    unsigned short* __restrict__ Khi, unsigned short* __restrict__ Klo) {
  __shared__ __align__(16) unsigned short Ah[2][128 * 32], Al[2][128 * 32];
  __shared__ __align__(16) unsigned short Bh[2][128 * 32], Bl[2][128 * 32];
  const int tid = threadIdx.x;
  const int lane = tid & 63, w = tid >> 6;
  const int lq = lane & 15, g = lane >> 4;
  const int n0 = blockIdx.x * 128;   // within stacked 2048
  const int m0 = blockIdx.y * 128;
  const int wm = (w >> 1) * 64, wn = (w & 1) * 64;

  f32x4 acc[4][4];
#pragma unroll
  for (int mi = 0; mi < 4; ++mi)
#pragma unroll
    for (int ni = 0; ni < 4; ++ni) acc[mi][ni] = (f32x4){0.f, 0.f, 0.f, 0.f};

  for (int k0 = 0; k0 < D_MODEL; k0 += 64) {
    __syncthreads();
#pragma unroll
    for (int half = 0; half < 2; ++half) {
      const int kc = k0 + half * 32;
#pragma unroll
      for (int it = 0; it < 2; ++it) {
        const int e = it * 256 + tid;      // 0..511
        const int r = e >> 2, c8 = (e & 3) * 8;
        glds16(&Xhi[(size_t)(m0 + r) * D_MODEL + kc + c8], &Ah[half][e * 8]);
        glds16(&Xlo[(size_t)(m0 + r) * D_MODEL + kc + c8], &Al[half][e * 8]);
        glds16(&Whi[(size_t)(n0 + r) * D_MODEL + kc + c8], &Bh[half][e * 8]);
        glds16(&Wlo[(size_t)(n0 + r) * D_MODEL + kc + c8], &Bl[half][e * 8]);
      }
    }
    __syncthreads();

#pragma unroll
    for (int half = 0; half < 2; ++half) {
      short8 ah[4], al[4], bh[4], bl[4];
#pragma unroll
      for (int i = 0; i < 4; ++i) {
        ah[i] = *(const short8*)&Ah[half][(wm + i * 16 + lq) * 32 + g * 8];
        al[i] = *(const short8*)&Al[half][(wm + i * 16 + lq) * 32 + g * 8];
        bh[i] = *(const short8*)&Bh[half][(wn + i * 16 + lq) * 32 + g * 8];
        bl[i] = *(const short8*)&Bl[half][(wn + i * 16 + lq) * 32 + g * 8];
      }
#pragma unroll
      for (int mi = 0; mi < 4; ++mi)
#pragma unroll
        for (int ni = 0; ni < 4; ++ni) {
          acc[mi][ni] = __builtin_amdgcn_mfma_f32_16x16x32_bf16(ah[mi], bh[ni], acc[mi][ni], 0, 0, 0);
          acc[mi][ni] = __builtin_amdgcn_mfma_f32_16x16x32_bf16(ah[mi], bl[ni], acc[mi][ni], 0, 0, 0);
          acc[mi][ni] = __builtin_amdgcn_mfma_f32_16x16x32_bf16(al[mi], bh[ni], acc[mi][ni], 0, 0, 0);
        }
    }
  }

  const bool isQ = (n0 < D_MODEL);
  unsigned short* Dhi = isQ ? Qhi : Khi;
  unsigned short* Dlo = isQ ? Qlo : Klo;
  const float sc = isQ ? QSCALE : 1.0f;
  const int nbase = n0 & (D_MODEL - 1);
#pragma unroll
  for (int mi = 0; mi < 4; ++mi)
#pragma unroll
    for (int ni = 0; ni < 4; ++ni) {
      const int gm = m0 + wm + mi * 16 + g * 4;
      const int gn = nbase + wn + ni * 16 + lq;
#pragma unroll
      for (int r = 0; r < 4; ++r) {
        unsigned short h, l;
        split2(acc[mi][ni][r] * sc, h, l);
        Dhi[(size_t)(gm + r) * D_MODEL + gn] = h;
        Dlo[(size_t)(gm + r) * D_MODEL + gn] = l;
      }
    }
}

// ---------------------------------------------------------------------------
// 128x64 plain bf16 GEMM (512 blocks = 2/CU), 2 k-tiles per barrier.
// CM 0: fp32 C row-major. CM 2: fp16 C transposed into Vt[b][h][dh][s].
// ---------------------------------------------------------------------------
template <int CM>
__global__ __launch_bounds__(256) void gemm_bn64_kernel(
    const unsigned short* __restrict__ A, const unsigned short* __restrict__ B,
    void* __restrict__ C) {
  __shared__ __align__(16) unsigned short Ah[2][128 * 32], Bh[2][64 * 32];
  const int tid = threadIdx.x;
  const int lane = tid & 63, w = tid >> 6;
  const int lq = lane & 15, g = lane >> 4;
  const int n0 = blockIdx.x * 64;
  const int m0 = blockIdx.y * 128;
  const int wm = (w >> 1) * 64, wn = (w & 1) * 32;

  f32x4 acc[4][2];
#pragma unroll
  for (int mi = 0; mi < 4; ++mi)
#pragma unroll
    for (int ni = 0; ni < 2; ++ni) acc[mi][ni] = (f32x4){0.f, 0.f, 0.f, 0.f};

  for (int k0 = 0; k0 < D_MODEL; k0 += 64) {
    __syncthreads();
#pragma unroll
    for (int half = 0; half < 2; ++half) {
      const int kc = k0 + half * 32;
#pragma unroll
      for (int it = 0; it < 2; ++it) {
        const int e = it * 256 + tid;
        const int r = e >> 2, c8 = (e & 3) * 8;
        glds16(&A[(size_t)(m0 + r) * D_MODEL + kc + c8], &Ah[half][e * 8]);
      }
      glds16(&B[(size_t)(n0 + (tid >> 2)) * D_MODEL + kc + (tid & 3) * 8],
             &Bh[half][tid * 8]);
    }
    __syncthreads();

#pragma unroll
    for (int half = 0; half < 2; ++half) {
      short8 ah[4], bh[2];
#pragma unroll
      for (int i = 0; i < 4; ++i)
        ah[i] = *(const short8*)&Ah[half][(wm + i * 16 + lq) * 32 + g * 8];
#pragma unroll
      for (int j = 0; j < 2; ++j)
        bh[j] = *(const short8*)&Bh[half][(wn + j * 16 + lq) * 32 + g * 8];
#pragma unroll
      for (int mi = 0; mi < 4; ++mi)
#pragma unroll
        for (int ni = 0; ni < 2; ++ni)
          acc[mi][ni] = __builtin_amdgcn_mfma_f32_16x16x32_bf16(ah[mi], bh[ni], acc[mi][ni], 0, 0, 0);
    }
  }

#pragma unroll
  for (int mi = 0; mi < 4; ++mi)
#pragma unroll
    for (int ni = 0; ni < 2; ++ni) {
      const int gm = m0 + wm + mi * 16 + g * 4;
      const int gn = n0 + wn + ni * 16 + lq;
      if constexpr (CM == 0) {
        float* Cf = (float*)C;
#pragma unroll
        for (int r = 0; r < 4; ++r)
          Cf[(size_t)(gm + r) * D_MODEL + gn] = acc[mi][ni][r];
      } else {  // Vt[b][h][dh][s] fp16; rows gm..gm+3 are 4 consecutive s
        const int bb = gm >> 11, s = gm & 2047;
        const int hh = gn >> 6, dh = gn & 63;
        uint2 pk;
        pk.x = pkh(acc[mi][ni][0], acc[mi][ni][1]);
        pk.y = pkh(acc[mi][ni][2], acc[mi][ni][3]);
        unsigned short* Vt = (unsigned short*)C;
        *(uint2*)&Vt[(((size_t)bb * N_HEADS + hh) * HEAD_DIM + dh) * SEQ + s] = pk;
      }
    }
}

// ---------------------------------------------------------------------------
// Split-K MFMA flash attention (causal), chunk C=12 kt-tiles. UNCHANGED
// from round 11 (proven: 83-89 us, VGPR 76, no spill).
// ---------------------------------------------------------------------------
#define PSTR 72  // LDS row stride in elements (64 data + 8 pad)

__global__ __launch_bounds__(256) void attn_mfma_kernel(
    const unsigned short* __restrict__ Qhi, const unsigned short* __restrict__ Qlo,
    const unsigned short* __restrict__ Khi, const unsigned short* __restrict__ Klo,
    const unsigned short* __restrict__ Vt,   // fp16 [B][H][HEAD_DIM][S]
    unsigned short* __restrict__ O,          // bf16 [B*S][D_MODEL] head-merged
    unsigned short* __restrict__ Opart,      // bf16 [1536][4096]
    float* __restrict__ Mpart, float* __restrict__ Lpart) {  // [1536][64]
  __shared__ __align__(16) unsigned short Khs[64 * PSTR];
  __shared__ __align__(16) unsigned short Kls[64 * PSTR];
  __shared__ __align__(16) unsigned short Vs[64 * PSTR];   // fp16
  __shared__ __align__(16) unsigned short Ps[64 * PSTR];   // fp16

  const int tid = threadIdx.x;
  const int lane = tid & 63;
  const int w = tid >> 6;
  const int lq = lane & 15;
  const int g = lane >> 4;
  const int q_blk = w * 16 + lq;
  const int x = blockIdx.x;
  const int h = blockIdx.y;
  const int b = blockIdx.z;

  int qt, kb, ke;
  if (x < 12)      { qt = 12 + x;                 kb = 0;  ke = 12; }
  else if (x < 28) { const int i = x - 12; qt = 24 + (i >> 1);
                     kb = (i & 1) * 12;           ke = kb + 12; }
  else if (x < 40) { qt = 23 - (x - 28);          kb = 12; ke = qt + 1; }
  else if (x < 48) { qt = 31 - (x - 40);          kb = 24; ke = qt + 1; }
  else             { qt = 59 - x;                 kb = 0;  ke = qt + 1; }
  const bool direct = (x >= 48);
  const int qr0 = qt * 64;

  const size_t base = ((size_t)b * SEQ) * D_MODEL + (size_t)h * HEAD_DIM;
  const unsigned short* Vtb = Vt + ((size_t)(b * N_HEADS + h) * HEAD_DIM) * SEQ;

  const size_t qoff = base + (size_t)(qr0 + q_blk) * D_MODEL;
  const short8 qh0 = *(const short8*)&Qhi[qoff + g * 8];
  const short8 qh1 = *(const short8*)&Qhi[qoff + g * 8 + 32];
  const short8 ql0 = *(const short8*)&Qlo[qoff + g * 8];
  const short8 ql1 = *(const short8*)&Qlo[qoff + g * 8 + 32];

  f32x4 Ot[4];
#pragma unroll
  for (int mt = 0; mt < 4; ++mt) Ot[mt] = (f32x4){0.f, 0.f, 0.f, 0.f};
  float m_run = -INFINITY, l_run = 0.f;

  for (int kt = kb; kt < ke; ++kt) {
    const int kr0 = kt * 64;
    __syncthreads();  // previous iteration's LDS reads done
#pragma unroll
    for (int it = 0; it < 2; ++it) {
      const int id = it * 256 + tid;
      const int r = id >> 3, c8 = (id & 7) * 8;
      const size_t koff = base + (size_t)(kr0 + r) * D_MODEL + c8;
      *(uint4*)&Khs[r * PSTR + c8] = *(const uint4*)&Khi[koff];
      *(uint4*)&Kls[r * PSTR + c8] = *(const uint4*)&Klo[koff];
      *(uint4*)&Vs[r * PSTR + c8]  = *(const uint4*)&Vtb[(size_t)r * SEQ + kr0 + c8];
    }
    __syncthreads();

    // S^T[k][q]: 4 k-subtiles x 6 MFMAs (hi/lo 3-term over two d-halves)
    f32x4 S[4];
#pragma unroll
    for (int st = 0; st < 4; ++st) {
      const unsigned short* khr = &Khs[(st * 16 + lq) * PSTR];
      const unsigned short* klr = &Kls[(st * 16 + lq) * PSTR];
      const short8 kh0 = *(const short8*)&khr[g * 8];
      const short8 kh1 = *(const short8*)&khr[g * 8 + 32];
      const short8 kl0 = *(const short8*)&klr[g * 8];
      const short8 kl1 = *(const short8*)&klr[g * 8 + 32];
      f32x4 s = (f32x4){0.f, 0.f, 0.f, 0.f};
      s = __builtin_amdgcn_mfma_f32_16x16x32_bf16(kh0, qh0, s, 0, 0, 0);
      s = __builtin_amdgcn_mfma_f32_16x16x32_bf16(kh1, qh1, s, 0, 0, 0);
      s = __builtin_amdgcn_mfma_f32_16x16x32_bf16(kh0, ql0, s, 0, 0, 0);
      s = __builtin_amdgcn_mfma_f32_16x16x32_bf16(kh1, ql1, s, 0, 0, 0);
      s = __builtin_amdgcn_mfma_f32_16x16x32_bf16(kl0, qh0, s, 0, 0, 0);
      s = __builtin_amdgcn_mfma_f32_16x16x32_bf16(kl1, qh1, s, 0, 0, 0);
      S[st] = s;
    }
    // V-fragments fp16 (independent of softmax; issue early)
    half8 vf0[4], vf1[4];
#pragma unroll
    for (int mt = 0; mt < 4; ++mt) {
      vf0[mt] = *(const half8*)&Vs[(mt * 16 + lq) * PSTR + g * 8];
      vf1[mt] = *(const half8*)&Vs[(mt * 16 + lq) * PSTR + g * 8 + 32];
    }

    // online softmax (exp2 domain; scale folded into Q)
    const bool diag = (kt == qt);
    float sv[16];
    float tmax = -3.0e38f;
#pragma unroll
    for (int st = 0; st < 4; ++st)
#pragma unroll
      for (int r = 0; r < 4; ++r) {
        float s = S[st][r];
        if (diag && (st * 16 + g * 4 + r) > q_blk) s = -1.0e30f;
        sv[st * 4 + r] = s;
        tmax = fmaxf(tmax, s);
      }
    tmax = fmaxf(tmax, __shfl_xor(tmax, 16));
    tmax = fmaxf(tmax, __shfl_xor(tmax, 32));
    const float m_new = fmaxf(m_run, tmax);
    const float alpha = exp2f(m_run - m_new);  // first iter: exp2(-inf)=0
    m_run = m_new;
    float psum = 0.f;
#pragma unroll
    for (int i = 0; i < 16; ++i) {
      sv[i] = exp2f(sv[i] - m_new);
      psum += sv[i];
    }
    // write P early (wave-private row, fp16 packed); bookkeeping hides latency
#pragma unroll
    for (int st = 0; st < 4; ++st) {
      uint2 pk;
      pk.x = pkh(sv[st * 4 + 0], sv[st * 4 + 1]);
      pk.y = pkh(sv[st * 4 + 2], sv[st * 4 + 3]);
      *(uint2*)&Ps[q_blk * PSTR + st * 16 + g * 4] = pk;
    }
    psum += __shfl_xor(psum, 16);
    psum += __shfl_xor(psum, 32);
    l_run = l_run * alpha + psum;
#pragma unroll
    for (int mt = 0; mt < 4; ++mt) {
      Ot[mt][0] *= alpha; Ot[mt][1] *= alpha;
      Ot[mt][2] *= alpha; Ot[mt][3] *= alpha;
    }
    const half8 pf0 = *(const half8*)&Ps[q_blk * PSTR + g * 8];
    const half8 pf1 = *(const half8*)&Ps[q_blk * PSTR + g * 8 + 32];
#pragma unroll
    for (int mt = 0; mt < 4; ++mt) {
      Ot[mt] = __builtin_amdgcn_mfma_f32_16x16x32_f16(vf0[mt], pf0, Ot[mt], 0, 0, 0);
      Ot[mt] = __builtin_amdgcn_mfma_f32_16x16x32_f16(vf1[mt], pf1, Ot[mt], 0, 0, 0);
    }
  }

  if (direct) {  // whole tile computed here: normalized direct write
    const float inv_l = 1.0f / l_run;
    unsigned short* orow = &O[qoff];
#pragma unroll
    for (int mt = 0; mt < 4; ++mt) {
      uint2 pk;
      pk.x = (unsigned)f2bf(Ot[mt][0] * inv_l) | ((unsigned)f2bf(Ot[mt][1] * inv_l) << 16);
      pk.y = (unsigned)f2bf(Ot[mt][2] * inv_l) | ((unsigned)f2bf(Ot[mt][3] * inv_l) << 16);
      *(uint2*)&orow[mt * 16 + g * 4] = pk;
    }
  } else {  // split chunk: unnormalized partial + (m,l)
    const int c = kb / 12;
    const int pbase = (qt < 24) ? ((qt - 12) * 2 + c) : (24 + (qt - 24) * 3 + c);
    const int pidx = (b * N_HEADS + h) * 48 + pbase;
    unsigned short* op = &Opart[(size_t)pidx * 4096 + (size_t)q_blk * 64];
#pragma unroll
    for (int mt = 0; mt < 4; ++mt) {
      uint2 pk;
      pk.x = (unsigned)f2bf(Ot[mt][0]) | ((unsigned)f2bf(Ot[mt][1]) << 16);
      pk.y = (unsigned)f2bf(Ot[mt][2]) | ((unsigned)f2bf(Ot[mt][3]) << 16);
      *(uint2*)&op[mt * 16 + g * 4] = pk;
    }
    if (g == 0) {  // one lane per q row (m/l wave-uniform across g)
      Mpart[pidx * 64 + q_blk] = m_run;
      Lpart[pidx * 64 + q_blk] = l_run;
    }
  }
}

// ---------------------------------------------------------------------------
// Merge nc (2 or 3) split-K partials per q-tile (qt>=12), exp2-domain.
// ---------------------------------------------------------------------------
__global__ __launch_bounds__(256) void attn_merge_kernel(
    const unsigned short* __restrict__ Opart, const float* __restrict__ Mpart,
    const float* __restrict__ Lpart, unsigned short* __restrict__ O) {
  const int qt = 12 + blockIdx.x;
  const int h = blockIdx.y, b = blockIdx.z;
  const int nc = (qt < 24) ? 2 : 3;
  const int pbase = (qt < 24) ? ((qt - 12) * 2) : (24 + (qt - 24) * 3);
  const int pidx0 = (b * N_HEADS + h) * 48 + pbase;
  const int t = threadIdx.x;
  const int row = t >> 2;
  const int c0 = (t & 3) * 16;

  float mi[3], li[3];
  float m = -INFINITY;
  for (int c = 0; c < nc; ++c) {
    mi[c] = Mpart[(pidx0 + c) * 64 + row];
    li[c] = Lpart[(pidx0 + c) * 64 + row];
    m = fmaxf(m, mi[c]);
  }
  float a[3], denom = 0.f;
  for (int c = 0; c < nc; ++c) {
    a[c] = exp2f(mi[c] - m);
    denom += a[c] * li[c];
  }
  const float inv = 1.0f / denom;

  float accv[16];
#pragma unroll
  for (int j = 0; j < 16; ++j) accv[j] = 0.f;
  for (int c = 0; c < nc; ++c) {
    const unsigned short* src =
        &Opart[(size_t)(pidx0 + c) * 4096 + (size_t)row * 64 + c0];
    const uint4 v0 = *(const uint4*)&src[0];
    const uint4 v1 = *(const uint4*)&src[8];
    const unsigned* u = (const unsigned*)&v0;
#pragma unroll
    for (int j = 0; j < 4; ++j) {
      accv[j * 2 + 0] += a[c] * bf2f((unsigned short)(u[j] & 0xFFFF));
      accv[j * 2 + 1] += a[c] * bf2f((unsigned short)(u[j] >> 16));
    }
    const unsigned* u1 = (const unsigned*)&v1;
#pragma unroll
    for (int j = 0; j < 4; ++j) {
      accv[8 + j * 2 + 0] += a[c] * bf2f((unsigned short)(u1[j] & 0xFFFF));
      accv[8 + j * 2 + 1] += a[c] * bf2f((unsigned short)(u1[j] >> 16));
    }
  }
  unsigned short* dst = &O[((size_t)b * SEQ + (size_t)qt * 64 + row) * D_MODEL +
                           (size_t)h * HEAD_DIM + c0];
  uint4 o0, o1;
  unsigned* po = (unsigned*)&o0;
#pragma unroll
  for (int j = 0; j < 4; ++j)
    po[j] = (unsigned)f2bf(accv[j * 2] * inv) |
            ((unsigned)f2bf(accv[j * 2 + 1] * inv) << 16);
  unsigned* p1 = (unsigned*)&o1;
#pragma unroll
  for (int j = 0; j < 4; ++j)
    p1[j] = (unsigned)f2bf(accv[8 + j * 2] * inv) |
            ((unsigned)f2bf(accv[8 + j * 2 + 1] * inv) << 16);
  *(uint4*)&dst[0] = o0;
  *(uint4*)&dst[8] = o1;
}

// ---------------------------------------------------------------------------
extern "C" void kernel_launch(void* const* d_in, const int* in_sizes, int n_in,
                              void* d_out, int out_size, void* d_ws, size_t ws_size,
                              hipStream_t stream) {
  const float* x  = (const float*)d_in[0];
  const float* qw = (const float*)d_in[1];
  const float* kw = (const float*)d_in[2];
  const float* vw = (const float*)d_in[3];
  const float* ow = (const float*)d_in[4];
  float* out = (float*)d_out;

  const int M = BATCH * SEQ;                       // 4096
  const size_t mat  = (size_t)M * D_MODEL;         // 4M elems
  const size_t wmat = (size_t)D_MODEL * D_MODEL;   // 1M elems

  // ws (ushort units), ~62.8 MB total:
  unsigned short* ws     = (unsigned short*)d_ws;
  unsigned short* Xhi    = ws;                     // [0,4M)  ; later At
  unsigned short* Xlo    = Xhi + mat;              // [4M,8M) ; later Vt (fp16)
  unsigned short* Wqk_hi = Xlo + mat;              // [8M,10M); later Opart
  unsigned short* Wqk_lo = Wqk_hi + 2 * wmat;      // [10M,12M); later Opart
  unsigned short* vwT    = Wqk_lo + 2 * wmat;      // [12M,13M); later Opart
  unsigned short* pad0   = vwT + wmat;             // [13M,14M); Opart tail
  unsigned short* Qhi    = pad0 + wmat;            // [14M,18M)
  unsigned short* Qlo    = Qhi + mat;              // [18M,22M)
  unsigned short* Khi    = Qlo + mat;              // [22M,26M)
  unsigned short* Klo    = Khi + mat;              // [26M,30M)
  unsigned short* owT    = Klo + mat;              // [30M,31M)
  float*          Mpart  = (float*)(owT + wmat);   // 1536*64 fp32 (384 KB)
  float*          Lpart  = Mpart + 1536 * 64;      // 384 KB
  unsigned short* At     = Xhi;     // alias (Xhi dead after V-GEMM)
  unsigned short* Vt     = Xlo;     // alias (Xlo dead after QK-GEMM)
  unsigned short* Opart  = Wqk_hi;  // alias [8M,14M) = 1536 x 4096 shorts

  prep_kernel<<<dim3(32, 32, 8), 256, 0, stream>>>(
      x, qw, kw, vw, ow, Xhi, Xlo, Wqk_hi, Wqk_lo, vwT, owT);

  gemm128_qk_kernel<<<dim3(16, 32), 256, 0, stream>>>(
      Xhi, Xlo, Wqk_hi, Wqk_lo, Qhi, Qlo, Khi, Klo);

  gemm_bn64_kernel<2><<<dim3(16, 32), 256, 0, stream>>>(Xhi, vwT, Vt);

  attn_mfma_kernel<<<dim3(60, N_HEADS, BATCH), 256, 0, stream>>>(
      Qhi, Qlo, Khi, Klo, Vt, At, Opart, Mpart, Lpart);

  attn_merge_kernel<<<dim3(20, N_HEADS, BATCH), 256, 0, stream>>>(
      Opart, Mpart, Lpart, At);

  gemm_bn64_kernel<0><<<dim3(16, 32), 256, 0, stream>>>(At, owT, out);
}